// Round 10
// baseline (130.255 us; speedup 1.0000x reference)
//
#include <hip/hip_runtime.h>
#include <hip/hip_bf16.h>
#include <stdint.h>

// Problem constants: B=IC=16, L=4096, OC=256, NC=8, CD=16, K=9
#define IK_ 144
typedef __fp16 h2 __attribute__((ext_vector_type(2)));

// workspace layout (float/dword element offsets)
#define WS_CWH 0u          // packed half2 weight pairs: [g=nk>>3][i][p][nk&7] : 16*16*5*8 = 10240 dwords
#define WS_CB  10240u      // cb[128] fp32
#define WS_U   10368u      // u[b][nk][s] bf16 at ((uint16_t*)(ws+WS_U)) + ((b*128+nk)<<12)+s (16.7 MB)

__device__ __forceinline__ uint32_t pack2bf(float a, float b) {
    const uint32_t lo = (uint32_t)__bfloat16_as_ushort(__float2bfloat16(a));
    const uint32_t hi = (uint32_t)__bfloat16_as_ushort(__float2bfloat16(b));
    return lo | (hi << 16);
}
#define BFLO(u) __uint_as_float((u) << 16)
#define BFHI(u) __uint_as_float((u) & 0xffff0000u)

// ---------------- K0: folded conv->caps weights, packed as half2 tap-pairs ----------------
// cw[nk,it] = sum_c caps_w[nk,c]*conv_w[c,it]; pairs (t=2p,2p+1), p=4 -> (t8, 0)
__global__ void k_cw(const float* __restrict__ caps_w,
                     const float* __restrict__ conv_w,
                     const float* __restrict__ conv_b,
                     const float* __restrict__ caps_b,
                     float* __restrict__ ws) {
    __shared__ float cwl[256];
    __shared__ float cwf[IK_];
    const int nk  = blockIdx.x;
    const int tid = threadIdx.x;
    cwl[tid] = caps_w[nk*256 + tid];
    __syncthreads();
    if (tid < IK_) {
        float a0 = 0.f, a1 = 0.f, a2 = 0.f, a3 = 0.f;
        for (int c = 0; c < 256; c += 4) {
            a0 += cwl[c+0] * conv_w[(c+0)*IK_ + tid];
            a1 += cwl[c+1] * conv_w[(c+1)*IK_ + tid];
            a2 += cwl[c+2] * conv_w[(c+2)*IK_ + tid];
            a3 += cwl[c+3] * conv_w[(c+3)*IK_ + tid];
        }
        cwf[tid] = (a0 + a1) + (a2 + a3);
    } else if (tid == IK_) {
        float a = 0.f;
        for (int c = 0; c < 256; ++c) a += cwl[c] * conv_b[c];
        ws[WS_CB + nk] = a + caps_b[nk];
    }
    __syncthreads();
    if (tid < 80) {                     // i = tid/5, p = tid%5
        const int i = tid / 5, p = tid - 5*i;
        const float w0 = cwf[i*9 + 2*p];
        const float w1 = (p < 4) ? cwf[i*9 + 2*p + 1] : 0.f;
        const h2 hp = __builtin_amdgcn_cvt_pkrtz(w0, w1);
        ((uint32_t*)ws)[WS_CWH + (((nk >> 3)*16 + i)*5 + p)*8 + (nk & 7)] =
            __builtin_bit_cast(uint32_t, hp);
    }
}

// ---------------- K1: u[b,nk,s] = conv(x[b], cw[nk]) + cb[nk] ----------------
// block = (stile 0..7 | oct 0..7 | b 0..15). 256 threads = 128 s-threads (4 s) x 2 nk-halves (8 nk).
// x tile staged ONCE in LDS as packed fp16 (16 rows x 264 dwords, 16.9 KB); odd-offset pairs built
// with v_alignbit (numerics identical to per-window cvt). Weights via wave-uniform s_load.
__global__ void __launch_bounds__(256) k_conv(const float* __restrict__ x,
                                              const float* __restrict__ wsc,
                                              float* __restrict__ ws) {
    const int tid   = threadIdx.x;
    const int b     = blockIdx.x & 15;
    const int oct   = (blockIdx.x >> 4) & 7;
    const int stile = blockIdx.x >> 7;
    const int sbase = stile << 9;

    // row i, dword d holds halves (x[b,i,sbase-4+2d], x[b,i,sbase-4+2d+1]); OOB = 0
    __shared__ uint32_t xh[16*264];

    for (int f = tid; f < 2096; f += 256) {        // 16 rows x 131 float4
        const int row = f / 131;
        const int col = f - row*131;
        const int s0  = sbase - 4 + (col << 2);
        float4 v;
        if (s0 < 0 || s0 > 4092) v = make_float4(0.f, 0.f, 0.f, 0.f);
        else v = *(const float4*)(x + (b << 16) + (row << 12) + s0);
        const uint32_t d0 = __builtin_bit_cast(uint32_t, __builtin_amdgcn_cvt_pkrtz(v.x, v.y));
        const uint32_t d1 = __builtin_bit_cast(uint32_t, __builtin_amdgcn_cvt_pkrtz(v.z, v.w));
        *(uint2*)(xh + row*264 + (col << 1)) = make_uint2(d0, d1);
    }
    __syncthreads();

    const int sid = tid & 127;
    const int g   = __builtin_amdgcn_readfirstlane(oct*2 + (tid >> 7));  // nk group of 8, uniform
    const uint32_t* __restrict__ cwp = (const uint32_t*)wsc + WS_CWH + g*640;   // [i][p][8]
    const float*    __restrict__ cbp = wsc + WS_CB + (g << 3);

    float4 acc[8];
    #pragma unroll
    for (int q = 0; q < 8; ++q) acc[q] = make_float4(0.f, 0.f, 0.f, 0.f);

    #pragma unroll 2
    for (int i = 0; i < 16; ++i) {
        // window halves f0..f15 = x[b,i, s0-4 .. s0+11], s0 = sbase + 4*sid
        const uint32_t* rw = xh + i*264 + (sid << 1);
        const uint2 a0 = *(const uint2*)(rw);
        const uint2 a1 = *(const uint2*)(rw + 2);
        const uint2 a2 = *(const uint2*)(rw + 4);
        const uint2 a3 = *(const uint2*)(rw + 6);
        const uint32_t D[8] = {a0.x, a0.y, a1.x, a1.y, a2.x, a2.y, a3.x, a3.y};
        uint32_t O[6];
        #pragma unroll
        for (int d = 0; d < 6; ++d)
            O[d] = __builtin_amdgcn_alignbit(D[d+1], D[d], 16);   // (f2d+1, f2d+2)
        const uint32_t* cpi = cwp + i*40;
        #pragma unroll
        for (int q = 0; q < 8; ++q) {
            #pragma unroll
            for (int p = 0; p < 5; ++p) {
                const h2 wv = __builtin_bit_cast(h2, cpi[p*8 + q]);   // uniform -> s_load
                acc[q].x = __builtin_amdgcn_fdot2(wv, __builtin_bit_cast(h2, D[p]),   acc[q].x, false);
                acc[q].y = __builtin_amdgcn_fdot2(wv, __builtin_bit_cast(h2, O[p]),   acc[q].y, false);
                acc[q].z = __builtin_amdgcn_fdot2(wv, __builtin_bit_cast(h2, D[p+1]), acc[q].z, false);
                acc[q].w = __builtin_amdgcn_fdot2(wv, __builtin_bit_cast(h2, O[p+1]), acc[q].w, false);
            }
        }
    }

    const int s = sbase + (sid << 2);
    uint16_t* up = (uint16_t*)(ws + WS_U);
    #pragma unroll
    for (int q = 0; q < 8; ++q) {
        const int nk = (g << 3) + q;
        const float cbv = cbp[q];
        const uint32_t p0 = pack2bf(acc[q].x + cbv, acc[q].y + cbv);
        const uint32_t p1 = pack2bf(acc[q].z + cbv, acc[q].w + cbv);
        *(uint2*)(up + (((size_t)((b << 7) + nk)) << 12) + s) = make_uint2(p0, p1);
    }
}

// ---------------- block-wide sum over 256 threads ----------------
__device__ __forceinline__ float block_sum(float v, float* red, int tid) {
    #pragma unroll
    for (int off = 32; off; off >>= 1) v += __shfl_down(v, off, 64);
    if ((tid & 63) == 0) red[tid >> 6] = v;
    __syncthreads();
    const float r = (red[0] + red[1]) + (red[2] + red[3]);
    __syncthreads();
    return r;
}

// ---------------- K2: c-mix + collapsed routing. block = (m 0..7, nk 0..127) ----------------
// bx = m*128 + nk : the 8 m-blocks of one nk share an XCD. b-loop software-pipelined (prefetch).
__global__ void __launch_bounds__(256) k_route(const float* __restrict__ wsc,
                                               const float* __restrict__ W,
                                               float* __restrict__ out) {
    const int tid = threadIdx.x;
    const int nk  = blockIdx.x & 127;
    const int m   = blockIdx.x >> 7;
    const int n   = nk >> 4, k = nk & 15;
    __shared__ float wl[16];
    __shared__ float red[4];
    if (tid < 16) wl[tid] = W[m*256 + tid*16 + k];
    __syncthreads();

    // softmax over b (redundant per thread; LDS broadcasts)
    float c[16], mx = -1e30f;
    #pragma unroll
    for (int b = 0; b < 16; ++b) { c[b] = wl[b]; mx = fmaxf(mx, c[b]); }
    float sum = 0.f;
    #pragma unroll
    for (int b = 0; b < 16; ++b) { c[b] = __expf(c[b] - mx); sum += c[b]; }
    const float inv = 1.f / sum;
    #pragma unroll
    for (int b = 0; b < 16; ++b) c[b] *= inv;

    float sv[16], Uv[16];
    #pragma unroll
    for (int j = 0; j < 16; ++j) { sv[j] = 0.f; Uv[j] = 0.f; }
    const uint16_t* ub = (const uint16_t*)(wsc + WS_U) + ((size_t)nk << 12) + (tid << 4);

    uint4 va = *(const uint4*)(ub);
    uint4 vb = *(const uint4*)(ub + 8);
    #pragma unroll
    for (int b = 0; b < 16; ++b) {
        uint4 na, nb;
        if (b < 15) {                                  // prefetch next b while unpacking current
            const uint16_t* pn = ub + ((size_t)(b + 1) << 19);
            na = *(const uint4*)(pn);
            nb = *(const uint4*)(pn + 8);
        }
        float uv[16];
        uv[0]=BFLO(va.x);  uv[1]=BFHI(va.x);  uv[2]=BFLO(va.y);  uv[3]=BFHI(va.y);
        uv[4]=BFLO(va.z);  uv[5]=BFHI(va.z);  uv[6]=BFLO(va.w);  uv[7]=BFHI(va.w);
        uv[8]=BFLO(vb.x);  uv[9]=BFHI(vb.x);  uv[10]=BFLO(vb.y); uv[11]=BFHI(vb.y);
        uv[12]=BFLO(vb.z); uv[13]=BFHI(vb.z); uv[14]=BFLO(vb.w); uv[15]=BFHI(vb.w);
        const float cb_ = c[b];
        #pragma unroll
        for (int j = 0; j < 16; ++j) {
            Uv[j] += uv[j];
            sv[j]  = fmaf(cb_, uv[j], sv[j]);
        }
        va = na; vb = nb;
    }

    float p = 0.f;
    #pragma unroll
    for (int j = 0; j < 16; ++j) p = fmaf(sv[j], sv[j], p);
    const float n0 = block_sum(p, red, tid);
    const float r0 = __fsqrt_rn(n0) / (1.f + n0);

    float s1[16];
    p = 0.f;
    #pragma unroll
    for (int j = 0; j < 16; ++j) {
        s1[j] = sv[j] * fmaf(r0*sv[j], Uv[j], 1.f);
        p = fmaf(s1[j], s1[j], p);
    }
    const float n1 = block_sum(p, red, tid);
    const float r1 = __fsqrt_rn(n1) / (1.f + n1);

    p = 0.f;
    #pragma unroll
    for (int j = 0; j < 16; ++j) {
        s1[j] = fmaf(r1*s1[j]*s1[j], Uv[j], sv[j]);   // reuse as s2
        p = fmaf(s1[j], s1[j], p);
    }
    const float n2 = block_sum(p, red, tid);
    const float r2 = __fsqrt_rn(n2) / (1.f + n2);

    float4* po = (float4*)(out + ((size_t)((m*16 + k)*8 + n) << 12) + (tid << 4));
    #pragma unroll
    for (int q = 0; q < 4; ++q)
        po[q] = make_float4(s1[4*q+0]*r2, s1[4*q+1]*r2, s1[4*q+2]*r2, s1[4*q+3]*r2);
}

extern "C" void kernel_launch(void* const* d_in, const int* in_sizes, int n_in,
                              void* d_out, int out_size, void* d_ws, size_t ws_size,
                              hipStream_t stream) {
    const float* x      = (const float*)d_in[0];
    const float* conv_w = (const float*)d_in[1];
    const float* conv_b = (const float*)d_in[2];
    const float* caps_w = (const float*)d_in[3];
    const float* caps_b = (const float*)d_in[4];
    const float* W      = (const float*)d_in[5];
    float* ws  = (float*)d_ws;
    float* out = (float*)d_out;

    hipLaunchKernelGGL(k_cw,    dim3(128),  dim3(256), 0, stream, caps_w, conv_w, conv_b, caps_b, ws);
    hipLaunchKernelGGL(k_conv,  dim3(1024), dim3(256), 0, stream, x, ws, ws);
    hipLaunchKernelGGL(k_route, dim3(1024), dim3(256), 0, stream, ws, W, out);
}

// Round 12
// 123.066 us; speedup vs baseline: 1.0584x; 1.0584x over previous
//
#include <hip/hip_runtime.h>
#include <hip/hip_bf16.h>
#include <stdint.h>

// Problem constants: B=IC=16, L=4096, OC=256, NC=8, CD=16, K=9
#define IK_ 144
typedef __fp16 h2 __attribute__((ext_vector_type(2)));

// workspace layout (float/dword element offsets)
#define WS_CWH 0u          // packed half2 weight pairs: [g=nk>>3][i][p][nk&7] : 16*16*5*8 = 10240 dwords
#define WS_CB  10240u      // cb[128] fp32
#define WS_U   10368u      // u[b][nk][s] bf16 at ((uint16_t*)(ws+WS_U)) + ((b*128+nk)<<12)+s (16.7 MB)

__device__ __forceinline__ uint32_t pack2bf(float a, float b) {
    const uint32_t lo = (uint32_t)__bfloat16_as_ushort(__float2bfloat16(a));
    const uint32_t hi = (uint32_t)__bfloat16_as_ushort(__float2bfloat16(b));
    return lo | (hi << 16);
}
#define BFLO(u) __uint_as_float((u) << 16)
#define BFHI(u) __uint_as_float((u) & 0xffff0000u)

// ---------------- K0: folded conv->caps weights, packed as half2 tap-pairs ----------------
// cw[nk,it] = sum_c caps_w[nk,c]*conv_w[c,it]; pairs (t=2p,2p+1), p=4 -> (t8, 0)
__global__ void k_cw(const float* __restrict__ caps_w,
                     const float* __restrict__ conv_w,
                     const float* __restrict__ conv_b,
                     const float* __restrict__ caps_b,
                     float* __restrict__ ws) {
    __shared__ float cwl[256];
    __shared__ float cwf[IK_];
    const int nk  = blockIdx.x;
    const int tid = threadIdx.x;
    cwl[tid] = caps_w[nk*256 + tid];
    __syncthreads();
    if (tid < IK_) {
        float a0 = 0.f, a1 = 0.f, a2 = 0.f, a3 = 0.f;
        for (int c = 0; c < 256; c += 4) {
            a0 += cwl[c+0] * conv_w[(c+0)*IK_ + tid];
            a1 += cwl[c+1] * conv_w[(c+1)*IK_ + tid];
            a2 += cwl[c+2] * conv_w[(c+2)*IK_ + tid];
            a3 += cwl[c+3] * conv_w[(c+3)*IK_ + tid];
        }
        cwf[tid] = (a0 + a1) + (a2 + a3);
    } else if (tid == IK_) {
        float a = 0.f;
        for (int c = 0; c < 256; ++c) a += cwl[c] * conv_b[c];
        ws[WS_CB + nk] = a + caps_b[nk];
    }
    __syncthreads();
    if (tid < 80) {                     // i = tid/5, p = tid%5
        const int i = tid / 5, p = tid - 5*i;
        const float w0 = cwf[i*9 + 2*p];
        const float w1 = (p < 4) ? cwf[i*9 + 2*p + 1] : 0.f;
        const h2 hp = __builtin_amdgcn_cvt_pkrtz(w0, w1);
        ((uint32_t*)ws)[WS_CWH + (((nk >> 3)*16 + i)*5 + p)*8 + (nk & 7)] =
            __builtin_bit_cast(uint32_t, hp);
    }
}

// ---------------- K1: u[b,nk,s] = conv(x[b], cw[nk]) + cb[nk], via v_dot2_f32_f16, bf16 store ----
// block = (stile 0..7 | oct 0..7 | b 0..15). 256 threads = 128 s-threads (4 s) x 2 nk-halves (8 nk).
// fp32 x tile staged ONCE in LDS; per-i window -> fp16 packed pairs in regs; weights via s_load.
// NOTE: no forced min-waves in __launch_bounds__ — natural register allocation (R11's forced
// 8-waves/EU cap triggered post-timing divergence, suspected spill-under-pressure hazard).
__global__ void __launch_bounds__(256) k_conv(const float* __restrict__ x,
                                              const float* __restrict__ wsc,
                                              float* __restrict__ ws) {
    const int tid   = threadIdx.x;
    const int b     = blockIdx.x & 15;
    const int oct   = (blockIdx.x >> 4) & 7;
    const int stile = blockIdx.x >> 7;
    const int sbase = stile << 9;

    __shared__ float xs[16*528];      // row i, elem e <-> x[b,i, sbase-4+e], e in [0,524), OOB = 0

    // divide-free staging: 16 threads per row, column stride 16 (cols 0..130 of float4)
    {
        const int row = tid >> 4;
        const int c0  = tid & 15;
        const float* xr = x + (b << 16) + (row << 12);
        float* lr = xs + row*528;
        #pragma unroll
        for (int k9 = 0; k9 < 9; ++k9) {
            const int col = c0 + (k9 << 4);
            if (col < 131) {
                const int j0 = sbase - 4 + (col << 2);
                float4 v;
                if (j0 < 0 || j0 > 4092) v = make_float4(0.f, 0.f, 0.f, 0.f);
                else v = *(const float4*)(xr + j0);
                *(float4*)(lr + (col << 2)) = v;
            }
        }
    }
    __syncthreads();

    const int sid = tid & 127;
    const int g   = __builtin_amdgcn_readfirstlane(oct*2 + (tid >> 7));  // nk group of 8, uniform
    const uint32_t* __restrict__ cwp = (const uint32_t*)wsc + WS_CWH + g*640;   // [i][p][8]
    const float*    __restrict__ cbp = wsc + WS_CB + (g << 3);

    float4 acc[8];
    #pragma unroll
    for (int q = 0; q < 8; ++q) acc[q] = make_float4(0.f, 0.f, 0.f, 0.f);

    #pragma unroll 2
    for (int i = 0; i < 16; ++i) {
        const float* rw = xs + i*528 + (sid << 2);
        const float4 w0 = ((const float4*)rw)[0];
        const float4 w1 = ((const float4*)rw)[1];
        const float4 w2 = ((const float4*)rw)[2];
        const float4 w3 = ((const float4*)rw)[3];
        const float f[14] = {w0.x,w0.y,w0.z,w0.w, w1.x,w1.y,w1.z,w1.w,
                             w2.x,w2.y,w2.z,w2.w, w3.x,w3.y};
        // E[d] = (f[2d], f[2d+1]) even-s pairs; O[d] = (f[2d+1], f[2d+2]) odd-s pairs
        h2 E[6], O[6];
        #pragma unroll
        for (int d = 0; d < 6; ++d) {
            E[d] = __builtin_amdgcn_cvt_pkrtz(f[2*d],   f[2*d+1]);
            O[d] = __builtin_amdgcn_cvt_pkrtz(f[2*d+1], f[2*d+2]);
        }
        const uint32_t* cpi = cwp + i*40;
        #pragma unroll
        for (int q = 0; q < 8; ++q) {
            #pragma unroll
            for (int p = 0; p < 5; ++p) {
                const h2 wv = __builtin_bit_cast(h2, cpi[p*8 + q]);   // uniform -> s_load
                acc[q].x = __builtin_amdgcn_fdot2(wv, E[p],   acc[q].x, false);
                acc[q].y = __builtin_amdgcn_fdot2(wv, O[p],   acc[q].y, false);
                acc[q].z = __builtin_amdgcn_fdot2(wv, E[p+1], acc[q].z, false);
                acc[q].w = __builtin_amdgcn_fdot2(wv, O[p+1], acc[q].w, false);
            }
        }
    }

    const int s = sbase + (sid << 2);
    uint16_t* up = (uint16_t*)(ws + WS_U);
    #pragma unroll
    for (int q = 0; q < 8; ++q) {
        const int nk = (g << 3) + q;
        const float cbv = cbp[q];
        const uint32_t p0 = pack2bf(acc[q].x + cbv, acc[q].y + cbv);
        const uint32_t p1 = pack2bf(acc[q].z + cbv, acc[q].w + cbv);
        *(uint2*)(up + (((size_t)((b << 7) + nk)) << 12) + s) = make_uint2(p0, p1);
    }
}

// ---------------- block-wide sum over 256 threads ----------------
__device__ __forceinline__ float block_sum(float v, float* red, int tid) {
    #pragma unroll
    for (int off = 32; off; off >>= 1) v += __shfl_down(v, off, 64);
    if ((tid & 63) == 0) red[tid >> 6] = v;
    __syncthreads();
    const float r = (red[0] + red[1]) + (red[2] + red[3]);
    __syncthreads();
    return r;
}

// ---------------- K2: c-mix + collapsed routing. block = (m 0..7, nk 0..127) ----------------
// bx = m*128 + nk : the 8 m-blocks of one nk share an XCD; per-XCD bf16 u set = 2 MB (half an L2).
__global__ void __launch_bounds__(256) k_route(const float* __restrict__ wsc,
                                               const float* __restrict__ W,
                                               float* __restrict__ out) {
    const int tid = threadIdx.x;
    const int nk  = blockIdx.x & 127;
    const int m   = blockIdx.x >> 7;
    const int n   = nk >> 4, k = nk & 15;
    __shared__ float wl[16];
    __shared__ float red[4];
    if (tid < 16) wl[tid] = W[m*256 + tid*16 + k];
    __syncthreads();

    // softmax over b (redundant per thread; LDS broadcasts)
    float c[16], mx = -1e30f;
    #pragma unroll
    for (int b = 0; b < 16; ++b) { c[b] = wl[b]; mx = fmaxf(mx, c[b]); }
    float sum = 0.f;
    #pragma unroll
    for (int b = 0; b < 16; ++b) { c[b] = __expf(c[b] - mx); sum += c[b]; }
    const float inv = 1.f / sum;
    #pragma unroll
    for (int b = 0; b < 16; ++b) c[b] *= inv;

    float sv[16], Uv[16];
    #pragma unroll
    for (int j = 0; j < 16; ++j) { sv[j] = 0.f; Uv[j] = 0.f; }
    const uint16_t* ub = (const uint16_t*)(wsc + WS_U) + ((size_t)nk << 12) + (tid << 4);
    for (int b = 0; b < 16; ++b) {
        const uint16_t* p16 = ub + ((size_t)b << 19);     // b stride = 128*4096 elems
        const uint4 va = *(const uint4*)(p16);
        const uint4 vb = *(const uint4*)(p16 + 8);
        float uv[16];
        uv[0]=BFLO(va.x);  uv[1]=BFHI(va.x);  uv[2]=BFLO(va.y);  uv[3]=BFHI(va.y);
        uv[4]=BFLO(va.z);  uv[5]=BFHI(va.z);  uv[6]=BFLO(va.w);  uv[7]=BFHI(va.w);
        uv[8]=BFLO(vb.x);  uv[9]=BFHI(vb.x);  uv[10]=BFLO(vb.y); uv[11]=BFHI(vb.y);
        uv[12]=BFLO(vb.z); uv[13]=BFHI(vb.z); uv[14]=BFLO(vb.w); uv[15]=BFHI(vb.w);
        const float cb_ = c[b];
        #pragma unroll
        for (int j = 0; j < 16; ++j) {
            Uv[j] += uv[j];
            sv[j]  = fmaf(cb_, uv[j], sv[j]);
        }
    }

    float p = 0.f;
    #pragma unroll
    for (int j = 0; j < 16; ++j) p = fmaf(sv[j], sv[j], p);
    const float n0 = block_sum(p, red, tid);
    const float r0 = __fsqrt_rn(n0) / (1.f + n0);

    float s1[16];
    p = 0.f;
    #pragma unroll
    for (int j = 0; j < 16; ++j) {
        s1[j] = sv[j] * fmaf(r0*sv[j], Uv[j], 1.f);
        p = fmaf(s1[j], s1[j], p);
    }
    const float n1 = block_sum(p, red, tid);
    const float r1 = __fsqrt_rn(n1) / (1.f + n1);

    p = 0.f;
    #pragma unroll
    for (int j = 0; j < 16; ++j) {
        s1[j] = fmaf(r1*s1[j]*s1[j], Uv[j], sv[j]);   // reuse as s2
        p = fmaf(s1[j], s1[j], p);
    }
    const float n2 = block_sum(p, red, tid);
    const float r2 = __fsqrt_rn(n2) / (1.f + n2);

    float4* po = (float4*)(out + ((size_t)((m*16 + k)*8 + n) << 12) + (tid << 4));
    #pragma unroll
    for (int q = 0; q < 4; ++q)
        po[q] = make_float4(s1[4*q+0]*r2, s1[4*q+1]*r2, s1[4*q+2]*r2, s1[4*q+3]*r2);
}

extern "C" void kernel_launch(void* const* d_in, const int* in_sizes, int n_in,
                              void* d_out, int out_size, void* d_ws, size_t ws_size,
                              hipStream_t stream) {
    const float* x      = (const float*)d_in[0];
    const float* conv_w = (const float*)d_in[1];
    const float* conv_b = (const float*)d_in[2];
    const float* caps_w = (const float*)d_in[3];
    const float* caps_b = (const float*)d_in[4];
    const float* W      = (const float*)d_in[5];
    float* ws  = (float*)d_ws;
    float* out = (float*)d_out;

    hipLaunchKernelGGL(k_cw,    dim3(128),  dim3(256), 0, stream, caps_w, conv_w, conv_b, caps_b, ws);
    hipLaunchKernelGGL(k_conv,  dim3(1024), dim3(256), 0, stream, x, ws, ws);
    hipLaunchKernelGGL(k_route, dim3(1024), dim3(256), 0, stream, ws, W, out);
}

// Round 13
// 121.522 us; speedup vs baseline: 1.0719x; 1.0127x over previous
//
#include <hip/hip_runtime.h>
#include <hip/hip_bf16.h>
#include <stdint.h>

// Problem constants: B=IC=16, L=4096, OC=256, NC=8, CD=16, K=9
#define IK_ 144
typedef __fp16 h2 __attribute__((ext_vector_type(2)));

// workspace layout (float/dword element offsets)
#define WS_CWH 0u          // packed half2 weight pairs: [g=nk>>3][i][p][nk&7] : 16*16*5*8 = 10240 dwords
#define WS_CB  10240u      // cb[128] fp32
#define WS_U   10368u      // u[b][nk][s] bf16 at ((uint16_t*)(ws+WS_U)) + ((b*128+nk)<<12)+s (16.7 MB)

__device__ __forceinline__ uint32_t pack2bf(float a, float b) {
    const uint32_t lo = (uint32_t)__bfloat16_as_ushort(__float2bfloat16(a));
    const uint32_t hi = (uint32_t)__bfloat16_as_ushort(__float2bfloat16(b));
    return lo | (hi << 16);
}
#define BFLO(u) __uint_as_float((u) << 16)
#define BFHI(u) __uint_as_float((u) & 0xffff0000u)

// ---------------- K0: folded conv->caps weights, packed as half2 tap-pairs ----------------
// cw[nk,it] = sum_c caps_w[nk,c]*conv_w[c,it]; pairs (t=2p,2p+1), p=4 -> (t8, 0)
__global__ void k_cw(const float* __restrict__ caps_w,
                     const float* __restrict__ conv_w,
                     const float* __restrict__ conv_b,
                     const float* __restrict__ caps_b,
                     float* __restrict__ ws) {
    __shared__ float cwl[256];
    __shared__ float cwf[IK_];
    const int nk  = blockIdx.x;
    const int tid = threadIdx.x;
    cwl[tid] = caps_w[nk*256 + tid];
    __syncthreads();
    if (tid < IK_) {
        float a0 = 0.f, a1 = 0.f, a2 = 0.f, a3 = 0.f;
        for (int c = 0; c < 256; c += 4) {
            a0 += cwl[c+0] * conv_w[(c+0)*IK_ + tid];
            a1 += cwl[c+1] * conv_w[(c+1)*IK_ + tid];
            a2 += cwl[c+2] * conv_w[(c+2)*IK_ + tid];
            a3 += cwl[c+3] * conv_w[(c+3)*IK_ + tid];
        }
        cwf[tid] = (a0 + a1) + (a2 + a3);
    } else if (tid == IK_) {
        float a = 0.f;
        for (int c = 0; c < 256; ++c) a += cwl[c] * conv_b[c];
        ws[WS_CB + nk] = a + caps_b[nk];
    }
    __syncthreads();
    if (tid < 80) {                     // i = tid/5, p = tid%5
        const int i = tid / 5, p = tid - 5*i;
        const float w0 = cwf[i*9 + 2*p];
        const float w1 = (p < 4) ? cwf[i*9 + 2*p + 1] : 0.f;
        const h2 hp = __builtin_amdgcn_cvt_pkrtz(w0, w1);
        ((uint32_t*)ws)[WS_CWH + (((nk >> 3)*16 + i)*5 + p)*8 + (nk & 7)] =
            __builtin_bit_cast(uint32_t, hp);
    }
}

// ---------------- K1: u[b,nk,s] = conv(x[b], cw[nk]) + cb[nk], via v_dot2_f32_f16, bf16 store ----
// block = (stile 0..7 | oct 0..7 | b 0..15). 256 threads = 128 s-threads (4 s) x 2 nk-halves (8 nk).
// i-loop CHUNKED by 4: batch 16 ds_read_b128 per chunk -> one lgkm drain per chunk instead of per i
// (s_load results force lgkmcnt(0); mixing per-i was the stall). Numerics identical to R12.
__global__ void __launch_bounds__(256) k_conv(const float* __restrict__ x,
                                              const float* __restrict__ wsc,
                                              float* __restrict__ ws) {
    const int tid   = threadIdx.x;
    const int b     = blockIdx.x & 15;
    const int oct   = (blockIdx.x >> 4) & 7;
    const int stile = blockIdx.x >> 7;
    const int sbase = stile << 9;

    __shared__ float xs[16*528];      // row i, elem e <-> x[b,i, sbase-4+e], e in [0,524), OOB = 0

    // divide-free staging: 16 threads per row, column stride 16 (cols 0..130 of float4)
    {
        const int row = tid >> 4;
        const int c0  = tid & 15;
        const float* xr = x + (b << 16) + (row << 12);
        float* lr = xs + row*528;
        #pragma unroll
        for (int k9 = 0; k9 < 9; ++k9) {
            const int col = c0 + (k9 << 4);
            if (col < 131) {
                const int j0 = sbase - 4 + (col << 2);
                float4 v;
                if (j0 < 0 || j0 > 4092) v = make_float4(0.f, 0.f, 0.f, 0.f);
                else v = *(const float4*)(xr + j0);
                *(float4*)(lr + (col << 2)) = v;
            }
        }
    }
    __syncthreads();

    const int sid = tid & 127;
    const int g   = __builtin_amdgcn_readfirstlane(oct*2 + (tid >> 7));  // nk group of 8, uniform
    const uint32_t* __restrict__ cwp = (const uint32_t*)wsc + WS_CWH + g*640;   // [i][p][8]
    const float*    __restrict__ cbp = wsc + WS_CB + (g << 3);

    float4 acc[8];
    #pragma unroll
    for (int q = 0; q < 8; ++q) acc[q] = make_float4(0.f, 0.f, 0.f, 0.f);

    #pragma unroll
    for (int c4 = 0; c4 < 4; ++c4) {
        // batch the LDS window loads for i = 4*c4 .. 4*c4+3 (16 independent ds_read_b128)
        float4 w[4][4];
        #pragma unroll
        for (int ii = 0; ii < 4; ++ii) {
            const float* rw = xs + (c4*4 + ii)*528 + (sid << 2);
            w[ii][0] = ((const float4*)rw)[0];
            w[ii][1] = ((const float4*)rw)[1];
            w[ii][2] = ((const float4*)rw)[2];
            w[ii][3] = ((const float4*)rw)[3];
        }
        #pragma unroll
        for (int ii = 0; ii < 4; ++ii) {
            const int i = c4*4 + ii;
            const float f[14] = {w[ii][0].x,w[ii][0].y,w[ii][0].z,w[ii][0].w,
                                 w[ii][1].x,w[ii][1].y,w[ii][1].z,w[ii][1].w,
                                 w[ii][2].x,w[ii][2].y,w[ii][2].z,w[ii][2].w,
                                 w[ii][3].x,w[ii][3].y};
            // E[d] = (f[2d], f[2d+1]) even-s pairs; O[d] = (f[2d+1], f[2d+2]) odd-s pairs
            h2 E[6], O[6];
            #pragma unroll
            for (int d = 0; d < 6; ++d) {
                E[d] = __builtin_amdgcn_cvt_pkrtz(f[2*d],   f[2*d+1]);
                O[d] = __builtin_amdgcn_cvt_pkrtz(f[2*d+1], f[2*d+2]);
            }
            const uint32_t* cpi = cwp + i*40;
            #pragma unroll
            for (int q = 0; q < 8; ++q) {
                #pragma unroll
                for (int p = 0; p < 5; ++p) {
                    const h2 wv = __builtin_bit_cast(h2, cpi[p*8 + q]);   // uniform -> s_load
                    acc[q].x = __builtin_amdgcn_fdot2(wv, E[p],   acc[q].x, false);
                    acc[q].y = __builtin_amdgcn_fdot2(wv, O[p],   acc[q].y, false);
                    acc[q].z = __builtin_amdgcn_fdot2(wv, E[p+1], acc[q].z, false);
                    acc[q].w = __builtin_amdgcn_fdot2(wv, O[p+1], acc[q].w, false);
                }
            }
        }
    }

    const int s = sbase + (sid << 2);
    uint16_t* up = (uint16_t*)(ws + WS_U);
    #pragma unroll
    for (int q = 0; q < 8; ++q) {
        const int nk = (g << 3) + q;
        const float cbv = cbp[q];
        const uint32_t p0 = pack2bf(acc[q].x + cbv, acc[q].y + cbv);
        const uint32_t p1 = pack2bf(acc[q].z + cbv, acc[q].w + cbv);
        *(uint2*)(up + (((size_t)((b << 7) + nk)) << 12) + s) = make_uint2(p0, p1);
    }
}

// ---------------- block-wide sum over 256 threads ----------------
__device__ __forceinline__ float block_sum(float v, float* red, int tid) {
    #pragma unroll
    for (int off = 32; off; off >>= 1) v += __shfl_down(v, off, 64);
    if ((tid & 63) == 0) red[tid >> 6] = v;
    __syncthreads();
    const float r = (red[0] + red[1]) + (red[2] + red[3]);
    __syncthreads();
    return r;
}

// ---------------- K2: c-mix + collapsed routing. block = (m 0..7, nk 0..127) ----------------
// bx = m*128 + nk : the 8 m-blocks of one nk share an XCD; per-XCD bf16 u set = 2 MB (half an L2).
__global__ void __launch_bounds__(256) k_route(const float* __restrict__ wsc,
                                               const float* __restrict__ W,
                                               float* __restrict__ out) {
    const int tid = threadIdx.x;
    const int nk  = blockIdx.x & 127;
    const int m   = blockIdx.x >> 7;
    const int n   = nk >> 4, k = nk & 15;
    __shared__ float wl[16];
    __shared__ float red[4];
    if (tid < 16) wl[tid] = W[m*256 + tid*16 + k];
    __syncthreads();

    // softmax over b (redundant per thread; LDS broadcasts)
    float c[16], mx = -1e30f;
    #pragma unroll
    for (int b = 0; b < 16; ++b) { c[b] = wl[b]; mx = fmaxf(mx, c[b]); }
    float sum = 0.f;
    #pragma unroll
    for (int b = 0; b < 16; ++b) { c[b] = __expf(c[b] - mx); sum += c[b]; }
    const float inv = 1.f / sum;
    #pragma unroll
    for (int b = 0; b < 16; ++b) c[b] *= inv;

    float sv[16], Uv[16];
    #pragma unroll
    for (int j = 0; j < 16; ++j) { sv[j] = 0.f; Uv[j] = 0.f; }
    const uint16_t* ub = (const uint16_t*)(wsc + WS_U) + ((size_t)nk << 12) + (tid << 4);
    for (int b = 0; b < 16; ++b) {
        const uint16_t* p16 = ub + ((size_t)b << 19);     // b stride = 128*4096 elems
        const uint4 va = *(const uint4*)(p16);
        const uint4 vb = *(const uint4*)(p16 + 8);
        float uv[16];
        uv[0]=BFLO(va.x);  uv[1]=BFHI(va.x);  uv[2]=BFLO(va.y);  uv[3]=BFHI(va.y);
        uv[4]=BFLO(va.z);  uv[5]=BFHI(va.z);  uv[6]=BFLO(va.w);  uv[7]=BFHI(va.w);
        uv[8]=BFLO(vb.x);  uv[9]=BFHI(vb.x);  uv[10]=BFLO(vb.y); uv[11]=BFHI(vb.y);
        uv[12]=BFLO(vb.z); uv[13]=BFHI(vb.z); uv[14]=BFLO(vb.w); uv[15]=BFHI(vb.w);
        const float cb_ = c[b];
        #pragma unroll
        for (int j = 0; j < 16; ++j) {
            Uv[j] += uv[j];
            sv[j]  = fmaf(cb_, uv[j], sv[j]);
        }
    }

    float p = 0.f;
    #pragma unroll
    for (int j = 0; j < 16; ++j) p = fmaf(sv[j], sv[j], p);
    const float n0 = block_sum(p, red, tid);
    const float r0 = __fsqrt_rn(n0) / (1.f + n0);

    float s1[16];
    p = 0.f;
    #pragma unroll
    for (int j = 0; j < 16; ++j) {
        s1[j] = sv[j] * fmaf(r0*sv[j], Uv[j], 1.f);
        p = fmaf(s1[j], s1[j], p);
    }
    const float n1 = block_sum(p, red, tid);
    const float r1 = __fsqrt_rn(n1) / (1.f + n1);

    p = 0.f;
    #pragma unroll
    for (int j = 0; j < 16; ++j) {
        s1[j] = fmaf(r1*s1[j]*s1[j], Uv[j], sv[j]);   // reuse as s2
        p = fmaf(s1[j], s1[j], p);
    }
    const float n2 = block_sum(p, red, tid);
    const float r2 = __fsqrt_rn(n2) / (1.f + n2);

    float4* po = (float4*)(out + ((size_t)((m*16 + k)*8 + n) << 12) + (tid << 4));
    #pragma unroll
    for (int q = 0; q < 4; ++q)
        po[q] = make_float4(s1[4*q+0]*r2, s1[4*q+1]*r2, s1[4*q+2]*r2, s1[4*q+3]*r2);
}

extern "C" void kernel_launch(void* const* d_in, const int* in_sizes, int n_in,
                              void* d_out, int out_size, void* d_ws, size_t ws_size,
                              hipStream_t stream) {
    const float* x      = (const float*)d_in[0];
    const float* conv_w = (const float*)d_in[1];
    const float* conv_b = (const float*)d_in[2];
    const float* caps_w = (const float*)d_in[3];
    const float* caps_b = (const float*)d_in[4];
    const float* W      = (const float*)d_in[5];
    float* ws  = (float*)d_ws;
    float* out = (float*)d_out;

    hipLaunchKernelGGL(k_cw,    dim3(128),  dim3(256), 0, stream, caps_w, conv_w, conv_b, caps_b, ws);
    hipLaunchKernelGGL(k_conv,  dim3(1024), dim3(256), 0, stream, x, ws, ws);
    hipLaunchKernelGGL(k_route, dim3(1024), dim3(256), 0, stream, ws, W, out);
}